// Round 15
// baseline (128.484 us; speedup 1.0000x reference)
//
#include <hip/hip_runtime.h>
#include <hip/hip_bf16.h>

// B=4, C=64, O=64, H=W=128, K=3, KK=9, PAD=1
// MFMA 16x16x32 bf16: A[m=lane&15][k=(lane>>4)*8+j], B[n=lane&15][k=...],
// C/D: col(n)=lane&15, row(m)=(lane>>4)*4+reg
// kappa = s*32 + q*8 + j  ->  tap = s>>1, c = (s&1)*32 + q*8 + j
//
// Round-15 (= r14 resubmit; broker timeout). launch_bounds (256,4) [r11 best].
// LDS band sampling: stage 5x24 padded window (16.3 KB), serve phase-4 corners
// from LDS (in-band lookup j=iyc-h+2, jx=ixc-w0+3; in-band iff j0>=0 && j1<=4 &&
// jx0>=0 && jx1<=23); rare out-of-band taps use clamped-global (bit-identical).
// Offconv reads the band (patch removed). Band col stride 68 shorts.
//
// ws layout (bytes):
//   xBp  [4][130][130][64] bf16 : ofs 0        (8.65 MB zero-halo padded NHWC bf16 of x)
//   Wb   [4][18][64][8]   bf16  : ofs 8652800  (deform weight B-frags)
//   OWb  [2][18][64][8]   bf16  : ofs 8726528  (offset_w B-frags)

typedef short short8 __attribute__((ext_vector_type(8)));
typedef float f32x4 __attribute__((ext_vector_type(4)));

#define SROW 36            // shorts per (s,p) row of sampB (72 B = 18 banks, conflict-free)
#define CSTR 68            // shorts per band col block (64 data + 4 pad)
#define RSTR (24 * CSTR)   // shorts per band row (1632)

static __device__ inline short bf16s(float f) {
    __hip_bfloat16 h = __float2bfloat16(f);
    return *(short*)&h;
}
static __device__ inline float lo2f(unsigned u) { return __uint_as_float(u << 16); }
static __device__ inline float hi2f(unsigned u) { return __uint_as_float(u & 0xffff0000u); }

// ---------------------------------------------------------------- fused prep + NCHW->padded-NHWC-bf16
// grid = 736: blocks 0..519 transpose (XCD-swizzled), 520..735 prep fragment packing.
__global__ void prep_transpose_kernel(const float* __restrict__ x,
                                      __hip_bfloat16* __restrict__ xBp,
                                      const float* __restrict__ offset_w, // [18][64][9]
                                      const float* __restrict__ weight,   // [64][64][9]
                                      __hip_bfloat16* __restrict__ Wb,    // [4][18][64][8]
                                      __hip_bfloat16* __restrict__ OWb)   // [2][18][64][8]
{
    __shared__ __align__(16) float lds[128 * 65];
    int raw = blockIdx.x;
    int t = threadIdx.x;

    if (raw >= 520) {                   // ---- prep path
        int id = (raw - 520) * 256 + t;
        if (id < 36864) {
            int j    = id & 7;
            int lane = (id >> 3) & 63;
            int id3  = id >> 9;
            int s    = id3 % 18;
            int otile = id3 / 18;
            int n = lane & 15, q = lane >> 4;
            int kap = s * 32 + q * 8 + j;      // kappa = k*64 + c
            int k = kap >> 6, c = kap & 63;
            int o = otile * 16 + n;
            Wb[id] = __float2bfloat16(weight[(o * 64 + c) * 9 + k]);
        }
        int id2 = id - 36864;
        if (id2 >= 0 && id2 < 18432) {
            int j    = id2 & 7;
            int lane = (id2 >> 3) & 63;
            int id3  = id2 >> 9;
            int s    = id3 % 18;
            int ntile = id3 / 18;
            int n = lane & 15, q = lane >> 4;
            int kap = s * 32 + q * 8 + j;
            int k = kap >> 6, c = kap & 63;
            int o = ntile * 16 + n;
            float v = (o < 18) ? offset_w[(o * 64 + c) * 9 + k] : 0.0f;
            OWb[id2] = __float2bfloat16(v);
        }
        return;
    }

    // ---- transpose path (XCD swizzle: 520 = 8*65)
    int blk = (raw & 7) * 65 + (raw >> 3);   // b*130 + r
    int b = blk / 130, r = blk - b * 130;
    unsigned* rowp = (unsigned*)(xBp + (size_t)(b * 130 + r) * 130 * 64); // 4160 dwords per row
    if (r == 0 || r == 129) {           // full zero row (halo)
        uint4 z = {0u, 0u, 0u, 0u};
        for (int i = 0; i < 5; ++i) {
            int e = i * 256 + t;
            if (e < 1040) ((uint4*)rowp)[e] = z;
        }
        return;
    }
    int h = r - 1;
    // load 64c x 128w floats as float4 along w: 2048 float4, 8 per thread
    const float4* x4 = (const float4*)x;
    size_t base4 = (size_t)b * 262144 + (size_t)h * 32;  // + c*4096 + w4
#pragma unroll
    for (int i = 0; i < 8; ++i) {
        int idx = i * 256 + t;          // idx = c*32 + w4
        int c = idx >> 5, w4 = idx & 31;
        float4 v = x4[base4 + (size_t)c * 4096 + w4];
        int wb = w4 * 4;
        lds[(wb + 0) * 65 + c] = v.x;
        lds[(wb + 1) * 65 + c] = v.y;
        lds[(wb + 2) * 65 + c] = v.z;
        lds[(wb + 3) * 65 + c] = v.w;
    }
    __syncthreads();
    unsigned* dst = rowp + 32;          // col 1 (each col = 64 shorts = 32 dwords)
    for (int i = 0; i < 16; ++i) {
        int L = i * 256 + t;            // L = ww*32 + c2
        int ww = L >> 5, c2 = L & 31;
        float f0 = lds[ww * 65 + c2 * 2];
        float f1 = lds[ww * 65 + c2 * 2 + 1];
        unsigned pk = ((unsigned)bf16s(f0) & 0xffffu) | ((unsigned)bf16s(f1) << 16);
        dst[L] = pk;
    }
    if (t < 64) {                       // zero halo cols 0 and 129
        int col = (t >> 5) * 129;
        rowp[col * 32 + (t & 31)] = 0u;
    }
}

// ---------------------------------------------------------------- phase-4 sampling helper
// Lane owns 8 channels (c8*8..c8*8+7) of pixel p; taps K0..K1-1.
// Corners served from the LDS band when in-window (the common case); rare
// out-of-window taps use the clamped-global path (bit-identical values).
template<int K0, int K1>
static __device__ inline void sample_taps(const short* __restrict__ band,
                                          const __hip_bfloat16* __restrict__ xb8,
                                          const float* __restrict__ offL,
                                          short* __restrict__ sampB,
                                          int h, int w0, int p, int c8)
{
    constexpr int NT = K1 - K0;
    float wa[NT], wb_[NT], wc[NT], wd[NT];
    uint4 r0[NT], r1[NT], r2[NT], r3[NT];
#pragma unroll
    for (int i = 0; i < NT; ++i) {
        int k = K0 + i;
        float offy = offL[(2 * k) * 16 + p];
        float offx = offL[(2 * k + 1) * 16 + p];
        float py = (float)(h - 1 + (k / 3)) + offy;
        float px = (float)(w0 + p - 1 + (k % 3)) + offx;
        float y0f = floorf(py), x0f = floorf(px);
        float wy1 = py - y0f, wx1 = px - x0f;
        float wy0 = 1.0f - wy1, wx0 = 1.0f - wx1;
        int iy = (int)y0f, ix = (int)x0f;
        int iy0 = min(max(iy, -1), 128);
        int ix0 = min(max(ix, -1), 128);
        int iy1 = min(max(iy + 1, -1), 128);
        int ix1 = min(max(ix + 1, -1), 128);
        wa[i] = wy0 * wx0;
        wb_[i] = wy0 * wx1;
        wc[i] = wy1 * wx0;
        wd[i] = wy1 * wx1;
        int j0  = iy0 - h + 2,  j1  = iy1 - h + 2;
        int jx0 = ix0 - w0 + 3, jx1 = ix1 - w0 + 3;
        if ((j0 >= 0) && (j1 <= 4) && (jx0 >= 0) && (jx1 <= 23)) {
            const short* b0 = band + j0 * RSTR + c8 * 8;
            const short* b1 = band + j1 * RSTR + c8 * 8;
            r0[i] = *(const uint4*)(b0 + jx0 * CSTR);
            r1[i] = *(const uint4*)(b0 + jx1 * CSTR);
            r2[i] = *(const uint4*)(b1 + jx0 * CSTR);
            r3[i] = *(const uint4*)(b1 + jx1 * CSTR);
        } else {
            int rb0 = iy0 * 130, rb1 = iy1 * 130;
            r0[i] = *(const uint4*)(xb8 + (rb0 + ix0) * 64);
            r1[i] = *(const uint4*)(xb8 + (rb0 + ix1) * 64);
            r2[i] = *(const uint4*)(xb8 + (rb1 + ix0) * 64);
            r3[i] = *(const uint4*)(xb8 + (rb1 + ix1) * 64);
        }
    }
#pragma unroll
    for (int i = 0; i < NT; ++i) {
        int k = K0 + i;
        short8 pk;
#define SAMP1(idx, comp, EXT) { \
            float sv = fmaf(wd[i], EXT(r3[i].comp), fmaf(wc[i], EXT(r2[i].comp), \
                       fmaf(wb_[i], EXT(r1[i].comp), wa[i] * EXT(r0[i].comp)))); \
            pk[idx] = bf16s(sv); }
        SAMP1(0, x, lo2f) SAMP1(1, x, hi2f)
        SAMP1(2, y, lo2f) SAMP1(3, y, hi2f)
        SAMP1(4, z, lo2f) SAMP1(5, z, hi2f)
        SAMP1(6, w, lo2f) SAMP1(7, w, hi2f)
#undef SAMP1
        int s = 2 * k + (c8 >> 2);
        *(short8*)&sampB[(s * 16 + p) * SROW + (c8 & 3) * 8] = pk;
    }
}

// ---------------------------------------------------------------- fused offconv + sampling + deform conv
// block = 16x1 row tile; 4 waves; grid = 4096 (XCD-swizzled: 8*512)
// LDS = band 16320 + sampB 20736 + offL 1152 = 38208 B -> 4 blocks/CU
__global__ __launch_bounds__(256, 4) void deform_kernel(
    const __hip_bfloat16* __restrict__ xBp, // [4][130][130][64] padded NHWC bf16
    const __hip_bfloat16* __restrict__ Wb,  // [4][18][64][8]
    const __hip_bfloat16* __restrict__ OWb, // [2][18][64][8]
    const float* __restrict__ offset_b,     // [18]
    const float* __restrict__ bias,         // [64]
    float* __restrict__ out)                // [4][64][128][128] NCHW
{
    __shared__ __align__(16) short band[5 * RSTR];         // 16320 B
    __shared__ __align__(16) short sampB[18 * 16 * SROW];  // 20736 B
    __shared__ __align__(16) float offL[288];              // [o][p]

    int t = threadIdx.x, wv = t >> 6, lane = t & 63;
    int bid = (blockIdx.x & 7) * 512 + (blockIdx.x >> 3); // XCD swizzle: contiguous (b,h) per XCD
    int b  = bid >> 10;
    int h  = (bid >> 3) & 127;
    int w0 = (bid & 7) << 4;

    // ---- phase 1: stage 5x24 band (padded rows clamp(h-1+j), cols clamp(w0-2+jx))
    // 120 px x 8 chunks of 16 B = 960 chunks; clamped duplicates at edges are harmless.
#pragma unroll
    for (int i = 0; i < 4; ++i) {
        int e = i * 256 + t;
        if (e < 960) {
            int px = e >> 3, part = e & 7;
            int j = px / 24, jx = px - j * 24;
            int prow = min(max(h - 1 + j, 0), 129);
            int pcol = min(max(w0 - 2 + jx, 0), 129);
            const uint4* src = (const uint4*)(xBp +
                ((size_t)(b * 130 + prow) * 130 + pcol) * 64 + part * 8);
            *(uint4*)&band[j * RSTR + jx * CSTR + part * 8] = *src;
        }
    }
    __syncthreads();

    // ---- phase 2: offset conv via MFMA (waves 0,1); A-frags from the band
    // (rows h-1..h+1 = j 1..3; padded col w0+n+kx -> jx = n+kx+2)
    if (wv < 2) {
        int n = lane & 15, q = lane >> 4;
        const short8* Bw = (const short8*)OWb + (wv * 18) * 64 + lane;
        f32x4 acc = {0.f, 0.f, 0.f, 0.f};
#pragma unroll
        for (int s = 0; s < 18; ++s) {
            int k = s >> 1;
            int ky = k / 3, kx = k - ky * 3;
            const short8 a = *(const short8*)&band[(ky + 1) * RSTR + (n + kx + 2) * CSTR
                                                   + (s & 1) * 32 + q * 8];
            acc = __builtin_amdgcn_mfma_f32_16x16x32_bf16(a, Bw[s * 64], acc, 0, 0, 0);
        }
        int o = wv * 16 + n;
        if (o < 18) {
            float bo = offset_b[o];
#pragma unroll
            for (int r = 0; r < 4; ++r)
                offL[o * 16 + q * 4 + r] = acc[r] + bo;
        }
    }
    __syncthreads();

    // ---- phase 4: sampling; 8 lanes/pixel, taps split over wave pairs (r9 partition)
    {
        int g8 = lane >> 3, c8 = lane & 7;
        int p = (wv & 1) * 8 + g8;
        const __hip_bfloat16* xb8 = xBp + (size_t)b * (130 * 130 * 64) + c8 * 8 + 131 * 64;
        if (wv < 2) sample_taps<0, 4>(band, xb8, offL, sampB, h, w0, p, c8);
        else        sample_taps<4, 9>(band, xb8, offL, sampB, h, w0, p, c8);
    }
    __syncthreads();

    // ---- phase 5: einsum via MFMA; wave wv = o-tile; 18 K-steps
    {
        int n = lane & 15, q = lane >> 4;
        int arow = n * SROW + q * 8;        // A: m = pixel = lane&15
        const short8* BwW = (const short8*)Wb + (wv * 18) * 64 + lane;
        f32x4 acc = {0.f, 0.f, 0.f, 0.f};
#pragma unroll
        for (int s = 0; s < 18; ++s) {
            const short8 a = *(const short8*)&sampB[s * (16 * SROW) + arow];
            acc = __builtin_amdgcn_mfma_f32_16x16x32_bf16(a, BwW[s * 64], acc, 0, 0, 0);
        }
        int o = wv * 16 + n;
        float bo = bias[o];
        // C/D: col = o, row m = q*4+reg = pixel -> w = w0 + q*4 + reg
        float4 st = {acc[0] + bo, acc[1] + bo, acc[2] + bo, acc[3] + bo};
        *(float4*)&out[(((size_t)b * 64 + o) * 128 + h) * 128 + w0 + q * 4] = st;
    }
}

// ---------------------------------------------------------------- launch
extern "C" void kernel_launch(void* const* d_in, const int* in_sizes, int n_in,
                              void* d_out, int out_size, void* d_ws, size_t ws_size,
                              hipStream_t stream) {
    const float* x        = (const float*)d_in[0];
    const float* offset_w = (const float*)d_in[1];
    const float* offset_b = (const float*)d_in[2];
    const float* weight   = (const float*)d_in[3];
    const float* bias     = (const float*)d_in[4];
    char* ws = (char*)d_ws;
    __hip_bfloat16* xBp = (__hip_bfloat16*)ws;                          // 8,652,800 B
    __hip_bfloat16* Wb  = (__hip_bfloat16*)(ws + 8652800);              // 73,728 B
    __hip_bfloat16* OWb = (__hip_bfloat16*)(ws + 8652800 + 73728);      // 36,864 B
    float* outp = (float*)d_out;

    hipLaunchKernelGGL(prep_transpose_kernel, dim3(736),  dim3(256), 0, stream,
                       x, xBp, offset_w, weight, Wb, OWb);
    hipLaunchKernelGGL(deform_kernel,         dim3(4096), dim3(256), 0, stream,
                       xBp, Wb, OWb, offset_b, bias, outp);
}

// Round 16
// 105.579 us; speedup vs baseline: 1.2170x; 1.2170x over previous
//
#include <hip/hip_runtime.h>
#include <hip/hip_bf16.h>

// B=4, C=64, O=64, H=W=128, K=3, KK=9, PAD=1
// MFMA 16x16x32 bf16: A[m=lane&15][k=(lane>>4)*8+j], B[n=lane&15][k=...],
// C/D: col(n)=lane&15, row(m)=(lane>>4)*4+reg
// kappa = s*32 + q*8 + j  ->  tap = s>>1, c = (s&1)*32 + q*8 + j
//
// Round-16: revert to r11 config (measured best 104.4 us): reg-batched gathers,
// launch_bounds(256,4), SROW=36/PROW=88 conflict-free LDS, no band (r15's LDS
// band collapsed VGPR 128->60 = un-batchable divergent loads, 58 us deform).
// New: dual-accumulator MFMA chains in phases 2/5 (even/odd s, summed at end)
// to halve the 18-deep dependent-MFMA latency chains. f32 reassociation only.
//
// ws layout (bytes):
//   xBp  [4][130][130][64] bf16 : ofs 0        (8.65 MB zero-halo padded NHWC bf16 of x)
//   Wb   [4][18][64][8]   bf16  : ofs 8652800  (deform weight B-frags)
//   OWb  [2][18][64][8]   bf16  : ofs 8726528  (offset_w B-frags)

typedef short short8 __attribute__((ext_vector_type(8)));
typedef float f32x4 __attribute__((ext_vector_type(4)));

#define SROW 36            // shorts per (s,p) row of sampB (72 B = 18 banks, conflict-free)
#define PROW 88            // shorts per pixel row of patch (64 data + 24 pad)

static __device__ inline short bf16s(float f) {
    __hip_bfloat16 h = __float2bfloat16(f);
    return *(short*)&h;
}
static __device__ inline float lo2f(unsigned u) { return __uint_as_float(u << 16); }
static __device__ inline float hi2f(unsigned u) { return __uint_as_float(u & 0xffff0000u); }

// ---------------------------------------------------------------- fused prep + NCHW->padded-NHWC-bf16
// grid = 736: blocks 0..519 transpose (XCD-swizzled), 520..735 prep fragment packing.
__global__ void prep_transpose_kernel(const float* __restrict__ x,
                                      __hip_bfloat16* __restrict__ xBp,
                                      const float* __restrict__ offset_w, // [18][64][9]
                                      const float* __restrict__ weight,   // [64][64][9]
                                      __hip_bfloat16* __restrict__ Wb,    // [4][18][64][8]
                                      __hip_bfloat16* __restrict__ OWb)   // [2][18][64][8]
{
    __shared__ __align__(16) float lds[128 * 65];
    int raw = blockIdx.x;
    int t = threadIdx.x;

    if (raw >= 520) {                   // ---- prep path
        int id = (raw - 520) * 256 + t;
        if (id < 36864) {
            int j    = id & 7;
            int lane = (id >> 3) & 63;
            int id3  = id >> 9;
            int s    = id3 % 18;
            int otile = id3 / 18;
            int n = lane & 15, q = lane >> 4;
            int kap = s * 32 + q * 8 + j;      // kappa = k*64 + c
            int k = kap >> 6, c = kap & 63;
            int o = otile * 16 + n;
            Wb[id] = __float2bfloat16(weight[(o * 64 + c) * 9 + k]);
        }
        int id2 = id - 36864;
        if (id2 >= 0 && id2 < 18432) {
            int j    = id2 & 7;
            int lane = (id2 >> 3) & 63;
            int id3  = id2 >> 9;
            int s    = id3 % 18;
            int ntile = id3 / 18;
            int n = lane & 15, q = lane >> 4;
            int kap = s * 32 + q * 8 + j;
            int k = kap >> 6, c = kap & 63;
            int o = ntile * 16 + n;
            float v = (o < 18) ? offset_w[(o * 64 + c) * 9 + k] : 0.0f;
            OWb[id2] = __float2bfloat16(v);
        }
        return;
    }

    // ---- transpose path (XCD swizzle: 520 = 8*65)
    int blk = (raw & 7) * 65 + (raw >> 3);   // b*130 + r
    int b = blk / 130, r = blk - b * 130;
    unsigned* rowp = (unsigned*)(xBp + (size_t)(b * 130 + r) * 130 * 64); // 4160 dwords per row
    if (r == 0 || r == 129) {           // full zero row (halo)
        uint4 z = {0u, 0u, 0u, 0u};
        for (int i = 0; i < 5; ++i) {
            int e = i * 256 + t;
            if (e < 1040) ((uint4*)rowp)[e] = z;
        }
        return;
    }
    int h = r - 1;
    // load 64c x 128w floats as float4 along w: 2048 float4, 8 per thread
    const float4* x4 = (const float4*)x;
    size_t base4 = (size_t)b * 262144 + (size_t)h * 32;  // + c*4096 + w4
#pragma unroll
    for (int i = 0; i < 8; ++i) {
        int idx = i * 256 + t;          // idx = c*32 + w4
        int c = idx >> 5, w4 = idx & 31;
        float4 v = x4[base4 + (size_t)c * 4096 + w4];
        int wb = w4 * 4;
        lds[(wb + 0) * 65 + c] = v.x;
        lds[(wb + 1) * 65 + c] = v.y;
        lds[(wb + 2) * 65 + c] = v.z;
        lds[(wb + 3) * 65 + c] = v.w;
    }
    __syncthreads();
    unsigned* dst = rowp + 32;          // col 1 (each col = 64 shorts = 32 dwords)
    for (int i = 0; i < 16; ++i) {
        int L = i * 256 + t;            // L = ww*32 + c2
        int ww = L >> 5, c2 = L & 31;
        float f0 = lds[ww * 65 + c2 * 2];
        float f1 = lds[ww * 65 + c2 * 2 + 1];
        unsigned pk = ((unsigned)bf16s(f0) & 0xffffu) | ((unsigned)bf16s(f1) << 16);
        dst[L] = pk;
    }
    if (t < 64) {                       // zero halo cols 0 and 129
        int col = (t >> 5) * 129;
        rowp[col * 32 + (t & 31)] = 0u;
    }
}

// ---------------------------------------------------------------- phase-4 sampling helper
// Lane owns 8 channels (c8*8..c8*8+7) of pixel p; taps K0..K1-1.
// Loop 1 issues ALL corner loads (statically-indexed reg arrays -> no scratch),
// loop 2 consumes. Zero-halo padding: clamp to [-1,128]; halo reads return 0.
template<int K0, int K1>
static __device__ inline void sample_taps(const __hip_bfloat16* __restrict__ xb8,
                                          const float* __restrict__ offL,
                                          short* __restrict__ sampB,
                                          int h, int w0, int p, int c8)
{
    constexpr int NT = K1 - K0;
    float wa[NT], wb_[NT], wc[NT], wd[NT];
    uint4 r0[NT], r1[NT], r2[NT], r3[NT];
#pragma unroll
    for (int i = 0; i < NT; ++i) {
        int k = K0 + i;
        float offy = offL[(2 * k) * 16 + p];
        float offx = offL[(2 * k + 1) * 16 + p];
        float py = (float)(h - 1 + (k / 3)) + offy;
        float px = (float)(w0 + p - 1 + (k % 3)) + offx;
        float y0f = floorf(py), x0f = floorf(px);
        float wy1 = py - y0f, wx1 = px - x0f;
        float wy0 = 1.0f - wy1, wx0 = 1.0f - wx1;
        int iy = (int)y0f, ix = (int)x0f;
        int iy0 = min(max(iy, -1), 128);
        int ix0 = min(max(ix, -1), 128);
        int iy1 = min(max(iy + 1, -1), 128);
        int ix1 = min(max(ix + 1, -1), 128);
        int rb0 = iy0 * 130, rb1 = iy1 * 130;
        r0[i] = *(const uint4*)(xb8 + (rb0 + ix0) * 64);
        r1[i] = *(const uint4*)(xb8 + (rb0 + ix1) * 64);
        r2[i] = *(const uint4*)(xb8 + (rb1 + ix0) * 64);
        r3[i] = *(const uint4*)(xb8 + (rb1 + ix1) * 64);
        wa[i] = wy0 * wx0;
        wb_[i] = wy0 * wx1;
        wc[i] = wy1 * wx0;
        wd[i] = wy1 * wx1;
    }
#pragma unroll
    for (int i = 0; i < NT; ++i) {
        int k = K0 + i;
        short8 pk;
#define SAMP1(idx, comp, EXT) { \
            float sv = fmaf(wd[i], EXT(r3[i].comp), fmaf(wc[i], EXT(r2[i].comp), \
                       fmaf(wb_[i], EXT(r1[i].comp), wa[i] * EXT(r0[i].comp)))); \
            pk[idx] = bf16s(sv); }
        SAMP1(0, x, lo2f) SAMP1(1, x, hi2f)
        SAMP1(2, y, lo2f) SAMP1(3, y, hi2f)
        SAMP1(4, z, lo2f) SAMP1(5, z, hi2f)
        SAMP1(6, w, lo2f) SAMP1(7, w, hi2f)
#undef SAMP1
        int s = 2 * k + (c8 >> 2);
        *(short8*)&sampB[(s * 16 + p) * SROW + (c8 & 3) * 8] = pk;
    }
}

// ---------------------------------------------------------------- fused offconv + sampling + deform conv
// block = 16x1 row tile; 4 waves; grid = 4096 (XCD-swizzled: 8*512)
// LDS = sampB 20736 (patch[54][88] aliases its head) + offL 1152 = 21888 B
// launch_bounds(256,4): VGPR cap 128 (measured optimum r9-r11).
__global__ __launch_bounds__(256, 4) void deform_kernel(
    const __hip_bfloat16* __restrict__ xBp, // [4][130][130][64] padded NHWC bf16
    const __hip_bfloat16* __restrict__ Wb,  // [4][18][64][8]
    const __hip_bfloat16* __restrict__ OWb, // [2][18][64][8]
    const float* __restrict__ offset_b,     // [18]
    const float* __restrict__ bias,         // [64]
    float* __restrict__ out)                // [4][64][128][128] NCHW
{
    __shared__ __align__(16) short sampB[18 * 16 * SROW];  // 20736 B
    __shared__ __align__(16) float offL[288];              // [o][p] (separate — NOT aliased)

    int t = threadIdx.x, wv = t >> 6, lane = t & 63;
    int bid = (blockIdx.x & 7) * 512 + (blockIdx.x >> 3); // XCD swizzle: contiguous (b,h) per XCD
    int b  = bid >> 10;
    int h  = (bid >> 3) & 127;
    int w0 = (bid & 7) << 4;

    short* patch = sampB;            // [54 px][PROW shorts]; px = row*18+col
                                     // rows = padded h..h+2, cols = padded w0..w0+17

    // ---- phase 1: stage 3x18x64 patch bf16 — branchless (halo is pre-zeroed), 16-B chunks
    {
#pragma unroll
        for (int i = 0; i < 2; ++i) {
            int e = i * 256 + t;            // 54*8 = 432 chunks of 16 B
            if (e < 432) {
                int px = e >> 3, part = e & 7;
                int row = px / 18, col = px - row * 18;
                const uint4* src = (const uint4*)(xBp +
                    ((size_t)((b * 130 + h + row) * 130) + w0 + col) * 64 + part * 8);
                *(uint4*)&patch[px * PROW + part * 8] = *src;
            }
        }
    }
    __syncthreads();

    // ---- phase 2: offset conv via MFMA (waves 0,1; o = wv*16+n; pixel p = q*4+reg)
    // dual accumulators (even/odd s) halve the dependent-MFMA chain.
    if (wv < 2) {
        int n = lane & 15, q = lane >> 4;
        const short8* Bw = (const short8*)OWb + (wv * 18) * 64 + lane;
        f32x4 acc0 = {0.f, 0.f, 0.f, 0.f};
        f32x4 acc1 = {0.f, 0.f, 0.f, 0.f};
#pragma unroll
        for (int s = 0; s < 18; s += 2) {
            int k0 = s >> 1;                 // taps: s, s+1 share k0? no: k = s>>1 for s, (s+1)>>1
            // s even: k=s/2; s+1 odd: k=s/2 as well (pairs (2k,2k+1) share tap k)
            int ky = k0 / 3, kx = k0 - ky * 3;
            int pix = ky * 18 + n + kx;
            const short8 a0 = *(const short8*)&patch[pix * PROW + 0 * 32 + q * 8];
            const short8 a1 = *(const short8*)&patch[pix * PROW + 1 * 32 + q * 8];
            acc0 = __builtin_amdgcn_mfma_f32_16x16x32_bf16(a0, Bw[s * 64], acc0, 0, 0, 0);
            acc1 = __builtin_amdgcn_mfma_f32_16x16x32_bf16(a1, Bw[(s + 1) * 64], acc1, 0, 0, 0);
        }
        f32x4 acc = acc0 + acc1;
        int o = wv * 16 + n;
        if (o < 18) {
            float bo = offset_b[o];
#pragma unroll
            for (int r = 0; r < 4; ++r)
                offL[o * 16 + q * 4 + r] = acc[r] + bo;
        }
    }
    __syncthreads();

    // ---- phase 4: sampling; 8 lanes/pixel (lane owns 8 channels), taps split over wave pairs
    // waves 0,1: taps 0..3; waves 2,3: taps 4..8. p = (wv&1)*8 + (lane>>3).
    // (sampB overwrites patch — safe: patch last read in phase 2, barrier between.)
    {
        int g8 = lane >> 3, c8 = lane & 7;
        int p = (wv & 1) * 8 + g8;
        const __hip_bfloat16* xb8 = xBp + (size_t)b * (130 * 130 * 64) + c8 * 8 + 131 * 64;
        if (wv < 2) sample_taps<0, 4>(xb8, offL, sampB, h, w0, p, c8);
        else        sample_taps<4, 9>(xb8, offL, sampB, h, w0, p, c8);
    }
    __syncthreads();

    // ---- phase 5: einsum via MFMA; wave wv = o-tile; dual accumulators (even/odd s)
    {
        int n = lane & 15, q = lane >> 4;
        int arow = n * SROW + q * 8;        // A: m = pixel = lane&15
        const short8* BwW = (const short8*)Wb + (wv * 18) * 64 + lane;
        f32x4 acc0 = {0.f, 0.f, 0.f, 0.f};
        f32x4 acc1 = {0.f, 0.f, 0.f, 0.f};
#pragma unroll
        for (int s = 0; s < 18; s += 2) {
            const short8 a0 = *(const short8*)&sampB[s * (16 * SROW) + arow];
            const short8 a1 = *(const short8*)&sampB[(s + 1) * (16 * SROW) + arow];
            acc0 = __builtin_amdgcn_mfma_f32_16x16x32_bf16(a0, BwW[s * 64], acc0, 0, 0, 0);
            acc1 = __builtin_amdgcn_mfma_f32_16x16x32_bf16(a1, BwW[(s + 1) * 64], acc1, 0, 0, 0);
        }
        f32x4 acc = acc0 + acc1;
        int o = wv * 16 + n;
        float bo = bias[o];
        // C/D: col = o, row m = q*4+reg = pixel -> w = w0 + q*4 + reg
        float4 st = {acc[0] + bo, acc[1] + bo, acc[2] + bo, acc[3] + bo};
        *(float4*)&out[(((size_t)b * 64 + o) * 128 + h) * 128 + w0 + q * 4] = st;
    }
}

// ---------------------------------------------------------------- launch
extern "C" void kernel_launch(void* const* d_in, const int* in_sizes, int n_in,
                              void* d_out, int out_size, void* d_ws, size_t ws_size,
                              hipStream_t stream) {
    const float* x        = (const float*)d_in[0];
    const float* offset_w = (const float*)d_in[1];
    const float* offset_b = (const float*)d_in[2];
    const float* weight   = (const float*)d_in[3];
    const float* bias     = (const float*)d_in[4];
    char* ws = (char*)d_ws;
    __hip_bfloat16* xBp = (__hip_bfloat16*)ws;                          // 8,652,800 B
    __hip_bfloat16* Wb  = (__hip_bfloat16*)(ws + 8652800);              // 73,728 B
    __hip_bfloat16* OWb = (__hip_bfloat16*)(ws + 8652800 + 73728);      // 36,864 B
    float* outp = (float*)d_out;

    hipLaunchKernelGGL(prep_transpose_kernel, dim3(736),  dim3(256), 0, stream,
                       x, xBp, offset_w, weight, Wb, OWb);
    hipLaunchKernelGGL(deform_kernel,         dim3(4096), dim3(256), 0, stream,
                       xBp, Wb, OWb, offset_b, bias, outp);
}

// Round 17
// 104.993 us; speedup vs baseline: 1.2237x; 1.0056x over previous
//
#include <hip/hip_runtime.h>
#include <hip/hip_bf16.h>

// B=4, C=64, O=64, H=W=128, K=3, KK=9, PAD=1
// MFMA 16x16x32 bf16: A[m=lane&15][k=(lane>>4)*8+j], B[n=lane&15][k=...],
// C/D: col(n)=lane&15, row(m)=(lane>>4)*4+reg
// kappa = s*32 + q*8 + j  ->  tap = s>>1, c = (s&1)*32 + q*8 + j
//
// FINAL (r11 config, measured best 104.4 us):
//  - fused offconv+sampling+einsum deform kernel (split-off offconv measured +5 us)
//  - zero-halo padded xBp -> branchless staging + clamp-to-[-1,128] sampling
//  - XCD swizzle: contiguous (b,h) slice per XCD (L2 locality)
//  - phase-4: 8 lanes/px, taps 4/5 over wave pairs, ALL corner loads batched into
//    statically-indexed reg arrays (latency fix: r8/r9 = -6 us)
//  - launch_bounds(256,4): VGPR cap 128 = measured optimum (85 worse, 170 worse)
//  - SROW=36 (72 B = 18 banks; 18n mod 32 injective -> conflict-free MFMA A-reads)
//    PROW=88 (4-way -> 2-way on offconv reads); r11: conflicts 1.87M->~0.5M, -1.8 us
//  - negative results (do not revisit): off_g split (+5), transpose re-partition
//    (+1.7), VGPR cap 170 (+1.6), LDS-band gather (+24: kills load batching,
//    VGPR 128->60), dual-acc MFMA chains (+1.2), 4-lane/px (+0.5)
//
// ws layout (bytes):
//   xBp  [4][130][130][64] bf16 : ofs 0        (8.65 MB zero-halo padded NHWC bf16 of x)
//   Wb   [4][18][64][8]   bf16  : ofs 8652800  (deform weight B-frags)
//   OWb  [2][18][64][8]   bf16  : ofs 8726528  (offset_w B-frags)

typedef short short8 __attribute__((ext_vector_type(8)));
typedef float f32x4 __attribute__((ext_vector_type(4)));

#define SROW 36            // shorts per (s,p) row of sampB (72 B = 18 banks, conflict-free)
#define PROW 88            // shorts per pixel row of patch (64 data + 24 pad)

static __device__ inline short bf16s(float f) {
    __hip_bfloat16 h = __float2bfloat16(f);
    return *(short*)&h;
}
static __device__ inline float lo2f(unsigned u) { return __uint_as_float(u << 16); }
static __device__ inline float hi2f(unsigned u) { return __uint_as_float(u & 0xffff0000u); }

// ---------------------------------------------------------------- fused prep + NCHW->padded-NHWC-bf16
// grid = 736: blocks 0..519 transpose (XCD-swizzled), 520..735 prep fragment packing.
__global__ void prep_transpose_kernel(const float* __restrict__ x,
                                      __hip_bfloat16* __restrict__ xBp,
                                      const float* __restrict__ offset_w, // [18][64][9]
                                      const float* __restrict__ weight,   // [64][64][9]
                                      __hip_bfloat16* __restrict__ Wb,    // [4][18][64][8]
                                      __hip_bfloat16* __restrict__ OWb)   // [2][18][64][8]
{
    __shared__ __align__(16) float lds[128 * 65];
    int raw = blockIdx.x;
    int t = threadIdx.x;

    if (raw >= 520) {                   // ---- prep path
        int id = (raw - 520) * 256 + t;
        if (id < 36864) {
            int j    = id & 7;
            int lane = (id >> 3) & 63;
            int id3  = id >> 9;
            int s    = id3 % 18;
            int otile = id3 / 18;
            int n = lane & 15, q = lane >> 4;
            int kap = s * 32 + q * 8 + j;      // kappa = k*64 + c
            int k = kap >> 6, c = kap & 63;
            int o = otile * 16 + n;
            Wb[id] = __float2bfloat16(weight[(o * 64 + c) * 9 + k]);
        }
        int id2 = id - 36864;
        if (id2 >= 0 && id2 < 18432) {
            int j    = id2 & 7;
            int lane = (id2 >> 3) & 63;
            int id3  = id2 >> 9;
            int s    = id3 % 18;
            int ntile = id3 / 18;
            int n = lane & 15, q = lane >> 4;
            int kap = s * 32 + q * 8 + j;
            int k = kap >> 6, c = kap & 63;
            int o = ntile * 16 + n;
            float v = (o < 18) ? offset_w[(o * 64 + c) * 9 + k] : 0.0f;
            OWb[id2] = __float2bfloat16(v);
        }
        return;
    }

    // ---- transpose path (XCD swizzle: 520 = 8*65)
    int blk = (raw & 7) * 65 + (raw >> 3);   // b*130 + r
    int b = blk / 130, r = blk - b * 130;
    unsigned* rowp = (unsigned*)(xBp + (size_t)(b * 130 + r) * 130 * 64); // 4160 dwords per row
    if (r == 0 || r == 129) {           // full zero row (halo)
        uint4 z = {0u, 0u, 0u, 0u};
        for (int i = 0; i < 5; ++i) {
            int e = i * 256 + t;
            if (e < 1040) ((uint4*)rowp)[e] = z;
        }
        return;
    }
    int h = r - 1;
    // load 64c x 128w floats as float4 along w: 2048 float4, 8 per thread
    const float4* x4 = (const float4*)x;
    size_t base4 = (size_t)b * 262144 + (size_t)h * 32;  // + c*4096 + w4
#pragma unroll
    for (int i = 0; i < 8; ++i) {
        int idx = i * 256 + t;          // idx = c*32 + w4
        int c = idx >> 5, w4 = idx & 31;
        float4 v = x4[base4 + (size_t)c * 4096 + w4];
        int wb = w4 * 4;
        lds[(wb + 0) * 65 + c] = v.x;
        lds[(wb + 1) * 65 + c] = v.y;
        lds[(wb + 2) * 65 + c] = v.z;
        lds[(wb + 3) * 65 + c] = v.w;
    }
    __syncthreads();
    unsigned* dst = rowp + 32;          // col 1 (each col = 64 shorts = 32 dwords)
    for (int i = 0; i < 16; ++i) {
        int L = i * 256 + t;            // L = ww*32 + c2
        int ww = L >> 5, c2 = L & 31;
        float f0 = lds[ww * 65 + c2 * 2];
        float f1 = lds[ww * 65 + c2 * 2 + 1];
        unsigned pk = ((unsigned)bf16s(f0) & 0xffffu) | ((unsigned)bf16s(f1) << 16);
        dst[L] = pk;
    }
    if (t < 64) {                       // zero halo cols 0 and 129
        int col = (t >> 5) * 129;
        rowp[col * 32 + (t & 31)] = 0u;
    }
}

// ---------------------------------------------------------------- phase-4 sampling helper
// Lane owns 8 channels (c8*8..c8*8+7) of pixel p; taps K0..K1-1.
// Loop 1 issues ALL corner loads (statically-indexed reg arrays -> no scratch),
// loop 2 consumes. Zero-halo padding: clamp to [-1,128]; halo reads return 0.
template<int K0, int K1>
static __device__ inline void sample_taps(const __hip_bfloat16* __restrict__ xb8,
                                          const float* __restrict__ offL,
                                          short* __restrict__ sampB,
                                          int h, int w0, int p, int c8)
{
    constexpr int NT = K1 - K0;
    float wa[NT], wb_[NT], wc[NT], wd[NT];
    uint4 r0[NT], r1[NT], r2[NT], r3[NT];
#pragma unroll
    for (int i = 0; i < NT; ++i) {
        int k = K0 + i;
        float offy = offL[(2 * k) * 16 + p];
        float offx = offL[(2 * k + 1) * 16 + p];
        float py = (float)(h - 1 + (k / 3)) + offy;
        float px = (float)(w0 + p - 1 + (k % 3)) + offx;
        float y0f = floorf(py), x0f = floorf(px);
        float wy1 = py - y0f, wx1 = px - x0f;
        float wy0 = 1.0f - wy1, wx0 = 1.0f - wx1;
        int iy = (int)y0f, ix = (int)x0f;
        int iy0 = min(max(iy, -1), 128);
        int ix0 = min(max(ix, -1), 128);
        int iy1 = min(max(iy + 1, -1), 128);
        int ix1 = min(max(ix + 1, -1), 128);
        int rb0 = iy0 * 130, rb1 = iy1 * 130;
        r0[i] = *(const uint4*)(xb8 + (rb0 + ix0) * 64);
        r1[i] = *(const uint4*)(xb8 + (rb0 + ix1) * 64);
        r2[i] = *(const uint4*)(xb8 + (rb1 + ix0) * 64);
        r3[i] = *(const uint4*)(xb8 + (rb1 + ix1) * 64);
        wa[i] = wy0 * wx0;
        wb_[i] = wy0 * wx1;
        wc[i] = wy1 * wx0;
        wd[i] = wy1 * wx1;
    }
#pragma unroll
    for (int i = 0; i < NT; ++i) {
        int k = K0 + i;
        short8 pk;
#define SAMP1(idx, comp, EXT) { \
            float sv = fmaf(wd[i], EXT(r3[i].comp), fmaf(wc[i], EXT(r2[i].comp), \
                       fmaf(wb_[i], EXT(r1[i].comp), wa[i] * EXT(r0[i].comp)))); \
            pk[idx] = bf16s(sv); }
        SAMP1(0, x, lo2f) SAMP1(1, x, hi2f)
        SAMP1(2, y, lo2f) SAMP1(3, y, hi2f)
        SAMP1(4, z, lo2f) SAMP1(5, z, hi2f)
        SAMP1(6, w, lo2f) SAMP1(7, w, hi2f)
#undef SAMP1
        int s = 2 * k + (c8 >> 2);
        *(short8*)&sampB[(s * 16 + p) * SROW + (c8 & 3) * 8] = pk;
    }
}

// ---------------------------------------------------------------- fused offconv + sampling + deform conv
// block = 16x1 row tile; 4 waves; grid = 4096 (XCD-swizzled: 8*512)
// LDS = sampB 20736 (patch[54][88] aliases its head) + offL 1152 = 21888 B
// launch_bounds(256,4): VGPR cap 128 (measured optimum r9-r11).
__global__ __launch_bounds__(256, 4) void deform_kernel(
    const __hip_bfloat16* __restrict__ xBp, // [4][130][130][64] padded NHWC bf16
    const __hip_bfloat16* __restrict__ Wb,  // [4][18][64][8]
    const __hip_bfloat16* __restrict__ OWb, // [2][18][64][8]
    const float* __restrict__ offset_b,     // [18]
    const float* __restrict__ bias,         // [64]
    float* __restrict__ out)                // [4][64][128][128] NCHW
{
    __shared__ __align__(16) short sampB[18 * 16 * SROW];  // 20736 B
    __shared__ __align__(16) float offL[288];              // [o][p] (separate — NOT aliased)

    int t = threadIdx.x, wv = t >> 6, lane = t & 63;
    int bid = (blockIdx.x & 7) * 512 + (blockIdx.x >> 3); // XCD swizzle: contiguous (b,h) per XCD
    int b  = bid >> 10;
    int h  = (bid >> 3) & 127;
    int w0 = (bid & 7) << 4;

    short* patch = sampB;            // [54 px][PROW shorts]; px = row*18+col
                                     // rows = padded h..h+2, cols = padded w0..w0+17

    // ---- phase 1: stage 3x18x64 patch bf16 — branchless (halo is pre-zeroed), 16-B chunks
    {
#pragma unroll
        for (int i = 0; i < 2; ++i) {
            int e = i * 256 + t;            // 54*8 = 432 chunks of 16 B
            if (e < 432) {
                int px = e >> 3, part = e & 7;
                int row = px / 18, col = px - row * 18;
                const uint4* src = (const uint4*)(xBp +
                    ((size_t)((b * 130 + h + row) * 130) + w0 + col) * 64 + part * 8);
                *(uint4*)&patch[px * PROW + part * 8] = *src;
            }
        }
    }
    __syncthreads();

    // ---- phase 2: offset conv via MFMA (waves 0,1; o = wv*16+n; pixel p = q*4+reg)
    if (wv < 2) {
        int n = lane & 15, q = lane >> 4;
        const short8* Bw = (const short8*)OWb + (wv * 18) * 64 + lane;
        f32x4 acc = {0.f, 0.f, 0.f, 0.f};
#pragma unroll
        for (int s = 0; s < 18; ++s) {
            int k = s >> 1;
            int ky = k / 3, kx = k - ky * 3;
            int pix = ky * 18 + n + kx;
            const short8 a = *(const short8*)&patch[pix * PROW + (s & 1) * 32 + q * 8];
            acc = __builtin_amdgcn_mfma_f32_16x16x32_bf16(a, Bw[s * 64], acc, 0, 0, 0);
        }
        int o = wv * 16 + n;
        if (o < 18) {
            float bo = offset_b[o];
#pragma unroll
            for (int r = 0; r < 4; ++r)
                offL[o * 16 + q * 4 + r] = acc[r] + bo;
        }
    }
    __syncthreads();

    // ---- phase 4: sampling; 8 lanes/pixel (lane owns 8 channels), taps split over wave pairs
    // waves 0,1: taps 0..3; waves 2,3: taps 4..8. p = (wv&1)*8 + (lane>>3).
    // (sampB overwrites patch — safe: patch last read in phase 2, barrier between.)
    {
        int g8 = lane >> 3, c8 = lane & 7;
        int p = (wv & 1) * 8 + g8;
        const __hip_bfloat16* xb8 = xBp + (size_t)b * (130 * 130 * 64) + c8 * 8 + 131 * 64;
        if (wv < 2) sample_taps<0, 4>(xb8, offL, sampB, h, w0, p, c8);
        else        sample_taps<4, 9>(xb8, offL, sampB, h, w0, p, c8);
    }
    __syncthreads();

    // ---- phase 5: einsum via MFMA; wave wv = o-tile; 18 K-steps
    {
        int n = lane & 15, q = lane >> 4;
        int arow = n * SROW + q * 8;        // A: m = pixel = lane&15
        const short8* BwW = (const short8*)Wb + (wv * 18) * 64 + lane;
        f32x4 acc = {0.f, 0.f, 0.f, 0.f};
#pragma unroll
        for (int s = 0; s < 18; ++s) {
            const short8 a = *(const short8*)&sampB[s * (16 * SROW) + arow];
            acc = __builtin_amdgcn_mfma_f32_16x16x32_bf16(a, BwW[s * 64], acc, 0, 0, 0);
        }
        int o = wv * 16 + n;
        float bo = bias[o];
        // C/D: col = o, row m = q*4+reg = pixel -> w = w0 + q*4 + reg
        float4 st = {acc[0] + bo, acc[1] + bo, acc[2] + bo, acc[3] + bo};
        *(float4*)&out[(((size_t)b * 64 + o) * 128 + h) * 128 + w0 + q * 4] = st;
    }
}

// ---------------------------------------------------------------- launch
extern "C" void kernel_launch(void* const* d_in, const int* in_sizes, int n_in,
                              void* d_out, int out_size, void* d_ws, size_t ws_size,
                              hipStream_t stream) {
    const float* x        = (const float*)d_in[0];
    const float* offset_w = (const float*)d_in[1];
    const float* offset_b = (const float*)d_in[2];
    const float* weight   = (const float*)d_in[3];
    const float* bias     = (const float*)d_in[4];
    char* ws = (char*)d_ws;
    __hip_bfloat16* xBp = (__hip_bfloat16*)ws;                          // 8,652,800 B
    __hip_bfloat16* Wb  = (__hip_bfloat16*)(ws + 8652800);              // 73,728 B
    __hip_bfloat16* OWb = (__hip_bfloat16*)(ws + 8652800 + 73728);      // 36,864 B
    float* outp = (float*)d_out;

    hipLaunchKernelGGL(prep_transpose_kernel, dim3(736),  dim3(256), 0, stream,
                       x, xBp, offset_w, weight, Wb, OWb);
    hipLaunchKernelGGL(deform_kernel,         dim3(4096), dim3(256), 0, stream,
                       xBp, Wb, OWb, offset_b, bias, outp);
}

// Round 18
// 104.010 us; speedup vs baseline: 1.2353x; 1.0095x over previous
//
#include <hip/hip_runtime.h>
#include <hip/hip_bf16.h>

// B=4, C=64, O=64, H=W=128, K=3, KK=9, PAD=1
// MFMA 16x16x32 bf16: A[m=lane&15][k=(lane>>4)*8+j], B[n=lane&15][k=...],
// C/D: col(n)=lane&15, row(m)=(lane>>4)*4+reg
//
// Round-18: 32-px blocks (grid 2048). All 4 waves busy in offconv (2 o-tiles x
// 2 pixel-tiles); phase-4 perfectly balanced (every wave: 8 px x 9 taps, two
// r11-style reg-batched chunks); barrier instances halved. LDS 43.8 KB -> 3
// blocks/CU (trade tested: phase-parallelism vs r11's ~15 waves).
// Negative results (do not revisit): off_g split (+5), transpose re-partition
// (+1.7), VGPR cap 170 @16px (+1.6), LDS-band gather (+24), dual-acc chains
// (+1.2), 4-lane/px (+0.5). Best so far: r11 config = 104.4.
//
// ws layout (bytes):
//   xBp  [4][130][130][64] bf16 : ofs 0        (8.65 MB zero-halo padded NHWC bf16 of x)
//   Wb   [4][18][64][8]   bf16  : ofs 8652800  (deform weight B-frags)
//   OWb  [2][18][64][8]   bf16  : ofs 8726528  (offset_w B-frags)

typedef short short8 __attribute__((ext_vector_type(8)));
typedef float f32x4 __attribute__((ext_vector_type(4)));

#define SROW 36            // shorts per (s,p) row of sampB (72 B = 18 banks, conflict-free)
#define PROW 88            // shorts per pixel row of patch (64 data + 24 pad)

static __device__ inline short bf16s(float f) {
    __hip_bfloat16 h = __float2bfloat16(f);
    return *(short*)&h;
}
static __device__ inline float lo2f(unsigned u) { return __uint_as_float(u << 16); }
static __device__ inline float hi2f(unsigned u) { return __uint_as_float(u & 0xffff0000u); }

// ---------------------------------------------------------------- fused prep + NCHW->padded-NHWC-bf16
// grid = 736: blocks 0..519 transpose (XCD-swizzled), 520..735 prep fragment packing.
__global__ void prep_transpose_kernel(const float* __restrict__ x,
                                      __hip_bfloat16* __restrict__ xBp,
                                      const float* __restrict__ offset_w, // [18][64][9]
                                      const float* __restrict__ weight,   // [64][64][9]
                                      __hip_bfloat16* __restrict__ Wb,    // [4][18][64][8]
                                      __hip_bfloat16* __restrict__ OWb)   // [2][18][64][8]
{
    __shared__ __align__(16) float lds[128 * 65];
    int raw = blockIdx.x;
    int t = threadIdx.x;

    if (raw >= 520) {                   // ---- prep path
        int id = (raw - 520) * 256 + t;
        if (id < 36864) {
            int j    = id & 7;
            int lane = (id >> 3) & 63;
            int id3  = id >> 9;
            int s    = id3 % 18;
            int otile = id3 / 18;
            int n = lane & 15, q = lane >> 4;
            int kap = s * 32 + q * 8 + j;      // kappa = k*64 + c
            int k = kap >> 6, c = kap & 63;
            int o = otile * 16 + n;
            Wb[id] = __float2bfloat16(weight[(o * 64 + c) * 9 + k]);
        }
        int id2 = id - 36864;
        if (id2 >= 0 && id2 < 18432) {
            int j    = id2 & 7;
            int lane = (id2 >> 3) & 63;
            int id3  = id2 >> 9;
            int s    = id3 % 18;
            int ntile = id3 / 18;
            int n = lane & 15, q = lane >> 4;
            int kap = s * 32 + q * 8 + j;
            int k = kap >> 6, c = kap & 63;
            int o = ntile * 16 + n;
            float v = (o < 18) ? offset_w[(o * 64 + c) * 9 + k] : 0.0f;
            OWb[id2] = __float2bfloat16(v);
        }
        return;
    }

    // ---- transpose path (XCD swizzle: 520 = 8*65)
    int blk = (raw & 7) * 65 + (raw >> 3);   // b*130 + r
    int b = blk / 130, r = blk - b * 130;
    unsigned* rowp = (unsigned*)(xBp + (size_t)(b * 130 + r) * 130 * 64); // 4160 dwords per row
    if (r == 0 || r == 129) {           // full zero row (halo)
        uint4 z = {0u, 0u, 0u, 0u};
        for (int i = 0; i < 5; ++i) {
            int e = i * 256 + t;
            if (e < 1040) ((uint4*)rowp)[e] = z;
        }
        return;
    }
    int h = r - 1;
    // load 64c x 128w floats as float4 along w: 2048 float4, 8 per thread
    const float4* x4 = (const float4*)x;
    size_t base4 = (size_t)b * 262144 + (size_t)h * 32;  // + c*4096 + w4
#pragma unroll
    for (int i = 0; i < 8; ++i) {
        int idx = i * 256 + t;          // idx = c*32 + w4
        int c = idx >> 5, w4 = idx & 31;
        float4 v = x4[base4 + (size_t)c * 4096 + w4];
        int wb = w4 * 4;
        lds[(wb + 0) * 65 + c] = v.x;
        lds[(wb + 1) * 65 + c] = v.y;
        lds[(wb + 2) * 65 + c] = v.z;
        lds[(wb + 3) * 65 + c] = v.w;
    }
    __syncthreads();
    unsigned* dst = rowp + 32;          // col 1 (each col = 64 shorts = 32 dwords)
    for (int i = 0; i < 16; ++i) {
        int L = i * 256 + t;            // L = ww*32 + c2
        int ww = L >> 5, c2 = L & 31;
        float f0 = lds[ww * 65 + c2 * 2];
        float f1 = lds[ww * 65 + c2 * 2 + 1];
        unsigned pk = ((unsigned)bf16s(f0) & 0xffffu) | ((unsigned)bf16s(f1) << 16);
        dst[L] = pk;
    }
    if (t < 64) {                       // zero halo cols 0 and 129
        int col = (t >> 5) * 129;
        rowp[col * 32 + (t & 31)] = 0u;
    }
}

// ---------------------------------------------------------------- phase-4 sampling helper (32-px tile)
// Lane owns 8 channels (c8*8..c8*8+7) of pixel p (p in [0,32)); taps K0..K1-1.
// Loop 1 issues ALL corner loads (statically-indexed reg arrays -> no scratch),
// loop 2 consumes. Zero-halo padding: clamp to [-1,128]; halo reads return 0.
template<int K0, int K1>
static __device__ inline void sample_taps(const __hip_bfloat16* __restrict__ xb8,
                                          const float* __restrict__ offL,
                                          short* __restrict__ sampB,
                                          int h, int w0, int p, int c8)
{
    constexpr int NT = K1 - K0;
    float wa[NT], wb_[NT], wc[NT], wd[NT];
    uint4 r0[NT], r1[NT], r2[NT], r3[NT];
#pragma unroll
    for (int i = 0; i < NT; ++i) {
        int k = K0 + i;
        float offy = offL[(2 * k) * 32 + p];
        float offx = offL[(2 * k + 1) * 32 + p];
        float py = (float)(h - 1 + (k / 3)) + offy;
        float px = (float)(w0 + p - 1 + (k % 3)) + offx;
        float y0f = floorf(py), x0f = floorf(px);
        float wy1 = py - y0f, wx1 = px - x0f;
        float wy0 = 1.0f - wy1, wx0 = 1.0f - wx1;
        int iy = (int)y0f, ix = (int)x0f;
        int iy0 = min(max(iy, -1), 128);
        int ix0 = min(max(ix, -1), 128);
        int iy1 = min(max(iy + 1, -1), 128);
        int ix1 = min(max(ix + 1, -1), 128);
        int rb0 = iy0 * 130, rb1 = iy1 * 130;
        r0[i] = *(const uint4*)(xb8 + (rb0 + ix0) * 64);
        r1[i] = *(const uint4*)(xb8 + (rb0 + ix1) * 64);
        r2[i] = *(const uint4*)(xb8 + (rb1 + ix0) * 64);
        r3[i] = *(const uint4*)(xb8 + (rb1 + ix1) * 64);
        wa[i] = wy0 * wx0;
        wb_[i] = wy0 * wx1;
        wc[i] = wy1 * wx0;
        wd[i] = wy1 * wx1;
    }
#pragma unroll
    for (int i = 0; i < NT; ++i) {
        int k = K0 + i;
        short8 pk;
#define SAMP1(idx, comp, EXT) { \
            float sv = fmaf(wd[i], EXT(r3[i].comp), fmaf(wc[i], EXT(r2[i].comp), \
                       fmaf(wb_[i], EXT(r1[i].comp), wa[i] * EXT(r0[i].comp)))); \
            pk[idx] = bf16s(sv); }
        SAMP1(0, x, lo2f) SAMP1(1, x, hi2f)
        SAMP1(2, y, lo2f) SAMP1(3, y, hi2f)
        SAMP1(4, z, lo2f) SAMP1(5, z, hi2f)
        SAMP1(6, w, lo2f) SAMP1(7, w, hi2f)
#undef SAMP1
        int s = 2 * k + (c8 >> 2);
        *(short8*)&sampB[(s * 32 + p) * SROW + (c8 & 3) * 8] = pk;
    }
}

// ---------------------------------------------------------------- fused offconv + sampling + deform conv
// block = 32x1 row tile; 4 waves; grid = 2048 (XCD-swizzled: 8*256)
// LDS = sampB 41472 (patch[102][88]=17952 aliases its head) + offL 2304 = 43776 B
// -> 3 blocks/CU; launch_bounds(256,3) (VGPR cap 170).
__global__ __launch_bounds__(256, 3) void deform_kernel(
    const __hip_bfloat16* __restrict__ xBp, // [4][130][130][64] padded NHWC bf16
    const __hip_bfloat16* __restrict__ Wb,  // [4][18][64][8]
    const __hip_bfloat16* __restrict__ OWb, // [2][18][64][8]
    const float* __restrict__ offset_b,     // [18]
    const float* __restrict__ bias,         // [64]
    float* __restrict__ out)                // [4][64][128][128] NCHW
{
    __shared__ __align__(16) short sampB[18 * 32 * SROW];  // 41472 B
    __shared__ __align__(16) float offL[18 * 2 * 32 / 2 * 2]; // [36][32]... = 576 f32, 2304 B

    int t = threadIdx.x, wv = t >> 6, lane = t & 63;
    int bid = (blockIdx.x & 7) * 256 + (blockIdx.x >> 3); // XCD swizzle: contiguous (b,h) per XCD
    int b  = bid >> 9;
    int h  = (bid >> 2) & 127;
    int w0 = (bid & 3) << 5;

    short* patch = sampB;            // [102 px][PROW shorts]; px = row*34+col
                                     // rows = padded h..h+2, cols = padded w0..w0+33

    // ---- phase 1: stage 3x34x64 patch bf16 — branchless (halo is pre-zeroed), 16-B chunks
    {
#pragma unroll
        for (int i = 0; i < 4; ++i) {
            int e = i * 256 + t;            // 102*8 = 816 chunks of 16 B
            if (e < 816) {
                int px = e >> 3, part = e & 7;
                int row = px / 34, col = px - row * 34;
                const uint4* src = (const uint4*)(xBp +
                    ((size_t)((b * 130 + h + row) * 130) + w0 + col) * 64 + part * 8);
                *(uint4*)&patch[px * PROW + part * 8] = *src;
            }
        }
    }
    __syncthreads();

    // ---- phase 2: offset conv via MFMA — ALL 4 waves: o-tile ot = wv&1, pixel-tile pt = wv>>1
    {
        int ot = wv & 1, pt = wv >> 1;
        int n = lane & 15, q = lane >> 4;
        const short8* Bw = (const short8*)OWb + (ot * 18) * 64 + lane;
        f32x4 acc = {0.f, 0.f, 0.f, 0.f};
#pragma unroll
        for (int s = 0; s < 18; ++s) {
            int k = s >> 1;
            int ky = k / 3, kx = k - ky * 3;
            int pix = ky * 34 + pt * 16 + n + kx;
            const short8 a = *(const short8*)&patch[pix * PROW + (s & 1) * 32 + q * 8];
            acc = __builtin_amdgcn_mfma_f32_16x16x32_bf16(a, Bw[s * 64], acc, 0, 0, 0);
        }
        int o = ot * 16 + n;
        if (o < 18) {
            float bo = offset_b[o];
#pragma unroll
            for (int r = 0; r < 4; ++r)
                offL[o * 32 + pt * 16 + q * 4 + r] = acc[r] + bo;
        }
    }
    __syncthreads();

    // ---- phase 4: sampling; 8 lanes/pixel; wave wv owns pixels wv*8+g8, ALL 9 taps
    // (two r11-style register batches: taps 0..3 then 4..8 — perfectly wave-balanced)
    {
        int g8 = lane >> 3, c8 = lane & 7;
        int p = wv * 8 + g8;
        const __hip_bfloat16* xb8 = xBp + (size_t)b * (130 * 130 * 64) + c8 * 8 + 131 * 64;
        sample_taps<0, 4>(xb8, offL, sampB, h, w0, p, c8);
        sample_taps<4, 9>(xb8, offL, sampB, h, w0, p, c8);
    }
    __syncthreads();

    // ---- phase 5: einsum via MFMA; wave wv = o-tile; 2 pixel-tiles (shared B-frag)
    {
        int n = lane & 15, q = lane >> 4;
        const short8* BwW = (const short8*)Wb + (wv * 18) * 64 + lane;
        f32x4 acc0 = {0.f, 0.f, 0.f, 0.f};
        f32x4 acc1 = {0.f, 0.f, 0.f, 0.f};
#pragma unroll
        for (int s = 0; s < 18; ++s) {
            const short8 bw = BwW[s * 64];
            const short8 a0 = *(const short8*)&sampB[(s * 32 + n) * SROW + q * 8];
            const short8 a1 = *(const short8*)&sampB[(s * 32 + 16 + n) * SROW + q * 8];
            acc0 = __builtin_amdgcn_mfma_f32_16x16x32_bf16(a0, bw, acc0, 0, 0, 0);
            acc1 = __builtin_amdgcn_mfma_f32_16x16x32_bf16(a1, bw, acc1, 0, 0, 0);
        }
        int o = wv * 16 + n;
        float bo = bias[o];
        float* ob = &out[(((size_t)b * 64 + o) * 128 + h) * 128 + w0 + q * 4];
        float4 st0 = {acc0[0] + bo, acc0[1] + bo, acc0[2] + bo, acc0[3] + bo};
        float4 st1 = {acc1[0] + bo, acc1[1] + bo, acc1[2] + bo, acc1[3] + bo};
        *(float4*)ob = st0;
        *(float4*)(ob + 16) = st1;
    }
}

// ---------------------------------------------------------------- launch
extern "C" void kernel_launch(void* const* d_in, const int* in_sizes, int n_in,
                              void* d_out, int out_size, void* d_ws, size_t ws_size,
                              hipStream_t stream) {
    const float* x        = (const float*)d_in[0];
    const float* offset_w = (const float*)d_in[1];
    const float* offset_b = (const float*)d_in[2];
    const float* weight   = (const float*)d_in[3];
    const float* bias     = (const float*)d_in[4];
    char* ws = (char*)d_ws;
    __hip_bfloat16* xBp = (__hip_bfloat16*)ws;                          // 8,652,800 B
    __hip_bfloat16* Wb  = (__hip_bfloat16*)(ws + 8652800);              // 73,728 B
    __hip_bfloat16* OWb = (__hip_bfloat16*)(ws + 8652800 + 73728);      // 36,864 B
    float* outp = (float*)d_out;

    hipLaunchKernelGGL(prep_transpose_kernel, dim3(736),  dim3(256), 0, stream,
                       x, xBp, offset_w, weight, Wb, OWb);
    hipLaunchKernelGGL(deform_kernel,         dim3(2048), dim3(256), 0, stream,
                       xBp, Wb, OWb, offset_b, bias, outp);
}

// Round 21
// 103.876 us; speedup vs baseline: 1.2369x; 1.0013x over previous
//
#include <hip/hip_runtime.h>
#include <hip/hip_bf16.h>

// B=4, C=64, O=64, H=W=128, K=3, KK=9, PAD=1
// MFMA 16x16x32 bf16: A[m=lane&15][k=(lane>>4)*8+j], B[n=lane&15][k=...],
// C/D: col(n)=lane&15, row(m)=(lane>>4)*4+reg
//
// FINAL = r18 (measured best 104.0 us): 32-px blocks (grid 2048), all 4 waves
// busy in offconv (2 o-tiles x 2 pixel-tiles), phase-4 perfectly balanced
// (every wave: 8 px x 9 taps, two reg-batched chunks), barriers halved vs 16-px.
// Negative results (do not revisit): off_g split (+5), transpose re-partition
// (+1.7), VGPR cap 170 @16px (+1.6), LDS-band gather (+24: kills load batching),
// dual-acc chains (+1.2), 4-lane/px (+0.5), cooperative single-launch fusion
// (FAILED: output never written — coop launch doesn't run under graph capture).
//
// ws layout (bytes):
//   xBp  [4][130][130][64] bf16 : ofs 0        (8.65 MB zero-halo padded NHWC bf16 of x)
//   Wb   [4][18][64][8]   bf16  : ofs 8652800  (deform weight B-frags)
//   OWb  [2][18][64][8]   bf16  : ofs 8726528  (offset_w B-frags)

typedef short short8 __attribute__((ext_vector_type(8)));
typedef float f32x4 __attribute__((ext_vector_type(4)));

#define SROW 36            // shorts per (s,p) row of sampB (72 B = 18 banks, conflict-free)
#define PROW 88            // shorts per pixel row of patch (64 data + 24 pad)

static __device__ inline short bf16s(float f) {
    __hip_bfloat16 h = __float2bfloat16(f);
    return *(short*)&h;
}
static __device__ inline float lo2f(unsigned u) { return __uint_as_float(u << 16); }
static __device__ inline float hi2f(unsigned u) { return __uint_as_float(u & 0xffff0000u); }

// ---------------------------------------------------------------- fused prep + NCHW->padded-NHWC-bf16
// grid = 736: blocks 0..519 transpose (XCD-swizzled), 520..735 prep fragment packing.
__global__ void prep_transpose_kernel(const float* __restrict__ x,
                                      __hip_bfloat16* __restrict__ xBp,
                                      const float* __restrict__ offset_w, // [18][64][9]
                                      const float* __restrict__ weight,   // [64][64][9]
                                      __hip_bfloat16* __restrict__ Wb,    // [4][18][64][8]
                                      __hip_bfloat16* __restrict__ OWb)   // [2][18][64][8]
{
    __shared__ __align__(16) float lds[128 * 65];
    int raw = blockIdx.x;
    int t = threadIdx.x;

    if (raw >= 520) {                   // ---- prep path
        int id = (raw - 520) * 256 + t;
        if (id < 36864) {
            int j    = id & 7;
            int lane = (id >> 3) & 63;
            int id3  = id >> 9;
            int s    = id3 % 18;
            int otile = id3 / 18;
            int n = lane & 15, q = lane >> 4;
            int kap = s * 32 + q * 8 + j;      // kappa = k*64 + c
            int k = kap >> 6, c = kap & 63;
            int o = otile * 16 + n;
            Wb[id] = __float2bfloat16(weight[(o * 64 + c) * 9 + k]);
        }
        int id2 = id - 36864;
        if (id2 >= 0 && id2 < 18432) {
            int j    = id2 & 7;
            int lane = (id2 >> 3) & 63;
            int id3  = id2 >> 9;
            int s    = id3 % 18;
            int ntile = id3 / 18;
            int n = lane & 15, q = lane >> 4;
            int kap = s * 32 + q * 8 + j;
            int k = kap >> 6, c = kap & 63;
            int o = ntile * 16 + n;
            float v = (o < 18) ? offset_w[(o * 64 + c) * 9 + k] : 0.0f;
            OWb[id2] = __float2bfloat16(v);
        }
        return;
    }

    // ---- transpose path (XCD swizzle: 520 = 8*65)
    int blk = (raw & 7) * 65 + (raw >> 3);   // b*130 + r
    int b = blk / 130, r = blk - b * 130;
    unsigned* rowp = (unsigned*)(xBp + (size_t)(b * 130 + r) * 130 * 64); // 4160 dwords per row
    if (r == 0 || r == 129) {           // full zero row (halo)
        uint4 z = {0u, 0u, 0u, 0u};
        for (int i = 0; i < 5; ++i) {
            int e = i * 256 + t;
            if (e < 1040) ((uint4*)rowp)[e] = z;
        }
        return;
    }
    int h = r - 1;
    // load 64c x 128w floats as float4 along w: 2048 float4, 8 per thread
    const float4* x4 = (const float4*)x;
    size_t base4 = (size_t)b * 262144 + (size_t)h * 32;  // + c*4096 + w4
#pragma unroll
    for (int i = 0; i < 8; ++i) {
        int idx = i * 256 + t;          // idx = c*32 + w4
        int c = idx >> 5, w4 = idx & 31;
        float4 v = x4[base4 + (size_t)c * 4096 + w4];
        int wb = w4 * 4;
        lds[(wb + 0) * 65 + c] = v.x;
        lds[(wb + 1) * 65 + c] = v.y;
        lds[(wb + 2) * 65 + c] = v.z;
        lds[(wb + 3) * 65 + c] = v.w;
    }
    __syncthreads();
    unsigned* dst = rowp + 32;          // col 1 (each col = 64 shorts = 32 dwords)
    for (int i = 0; i < 16; ++i) {
        int L = i * 256 + t;            // L = ww*32 + c2
        int ww = L >> 5, c2 = L & 31;
        float f0 = lds[ww * 65 + c2 * 2];
        float f1 = lds[ww * 65 + c2 * 2 + 1];
        unsigned pk = ((unsigned)bf16s(f0) & 0xffffu) | ((unsigned)bf16s(f1) << 16);
        dst[L] = pk;
    }
    if (t < 64) {                       // zero halo cols 0 and 129
        int col = (t >> 5) * 129;
        rowp[col * 32 + (t & 31)] = 0u;
    }
}

// ---------------------------------------------------------------- phase-4 sampling helper (32-px tile)
// Lane owns 8 channels (c8*8..c8*8+7) of pixel p (p in [0,32)); taps K0..K1-1.
// Loop 1 issues ALL corner loads (statically-indexed reg arrays -> no scratch),
// loop 2 consumes. Zero-halo padding: clamp to [-1,128]; halo reads return 0.
template<int K0, int K1>
static __device__ inline void sample_taps(const __hip_bfloat16* __restrict__ xb8,
                                          const float* __restrict__ offL,
                                          short* __restrict__ sampB,
                                          int h, int w0, int p, int c8)
{
    constexpr int NT = K1 - K0;
    float wa[NT], wb_[NT], wc[NT], wd[NT];
    uint4 r0[NT], r1[NT], r2[NT], r3[NT];
#pragma unroll
    for (int i = 0; i < NT; ++i) {
        int k = K0 + i;
        float offy = offL[(2 * k) * 32 + p];
        float offx = offL[(2 * k + 1) * 32 + p];
        float py = (float)(h - 1 + (k / 3)) + offy;
        float px = (float)(w0 + p - 1 + (k % 3)) + offx;
        float y0f = floorf(py), x0f = floorf(px);
        float wy1 = py - y0f, wx1 = px - x0f;
        float wy0 = 1.0f - wy1, wx0 = 1.0f - wx1;
        int iy = (int)y0f, ix = (int)x0f;
        int iy0 = min(max(iy, -1), 128);
        int ix0 = min(max(ix, -1), 128);
        int iy1 = min(max(iy + 1, -1), 128);
        int ix1 = min(max(ix + 1, -1), 128);
        int rb0 = iy0 * 130, rb1 = iy1 * 130;
        r0[i] = *(const uint4*)(xb8 + (rb0 + ix0) * 64);
        r1[i] = *(const uint4*)(xb8 + (rb0 + ix1) * 64);
        r2[i] = *(const uint4*)(xb8 + (rb1 + ix0) * 64);
        r3[i] = *(const uint4*)(xb8 + (rb1 + ix1) * 64);
        wa[i] = wy0 * wx0;
        wb_[i] = wy0 * wx1;
        wc[i] = wy1 * wx0;
        wd[i] = wy1 * wx1;
    }
#pragma unroll
    for (int i = 0; i < NT; ++i) {
        int k = K0 + i;
        short8 pk;
#define SAMP1(idx, comp, EXT) { \
            float sv = fmaf(wd[i], EXT(r3[i].comp), fmaf(wc[i], EXT(r2[i].comp), \
                       fmaf(wb_[i], EXT(r1[i].comp), wa[i] * EXT(r0[i].comp)))); \
            pk[idx] = bf16s(sv); }
        SAMP1(0, x, lo2f) SAMP1(1, x, hi2f)
        SAMP1(2, y, lo2f) SAMP1(3, y, hi2f)
        SAMP1(4, z, lo2f) SAMP1(5, z, hi2f)
        SAMP1(6, w, lo2f) SAMP1(7, w, hi2f)
#undef SAMP1
        int s = 2 * k + (c8 >> 2);
        *(short8*)&sampB[(s * 32 + p) * SROW + (c8 & 3) * 8] = pk;
    }
}

// ---------------------------------------------------------------- fused offconv + sampling + deform conv
// block = 32x1 row tile; 4 waves; grid = 2048 (XCD-swizzled: 8*256)
// LDS = sampB 41472 (patch[102][88]=17952 aliases its head) + offL 2304 = 43776 B
// -> 3 blocks/CU; launch_bounds(256,3) (VGPR cap 170).
__global__ __launch_bounds__(256, 3) void deform_kernel(
    const __hip_bfloat16* __restrict__ xBp, // [4][130][130][64] padded NHWC bf16
    const __hip_bfloat16* __restrict__ Wb,  // [4][18][64][8]
    const __hip_bfloat16* __restrict__ OWb, // [2][18][64][8]
    const float* __restrict__ offset_b,     // [18]
    const float* __restrict__ bias,         // [64]
    float* __restrict__ out)                // [4][64][128][128] NCHW
{
    __shared__ __align__(16) short sampB[18 * 32 * SROW];  // 41472 B
    __shared__ __align__(16) float offL[18 * 2 * 32 / 2 * 2]; // 576 f32, 2304 B

    int t = threadIdx.x, wv = t >> 6, lane = t & 63;
    int bid = (blockIdx.x & 7) * 256 + (blockIdx.x >> 3); // XCD swizzle: contiguous (b,h) per XCD
    int b  = bid >> 9;
    int h  = (bid >> 2) & 127;
    int w0 = (bid & 3) << 5;

    short* patch = sampB;            // [102 px][PROW shorts]; px = row*34+col
                                     // rows = padded h..h+2, cols = padded w0..w0+33

    // ---- phase 1: stage 3x34x64 patch bf16 — branchless (halo is pre-zeroed), 16-B chunks
    {
#pragma unroll
        for (int i = 0; i < 4; ++i) {
            int e = i * 256 + t;            // 102*8 = 816 chunks of 16 B
            if (e < 816) {
                int px = e >> 3, part = e & 7;
                int row = px / 34, col = px - row * 34;
                const uint4* src = (const uint4*)(xBp +
                    ((size_t)((b * 130 + h + row) * 130) + w0 + col) * 64 + part * 8);
                *(uint4*)&patch[px * PROW + part * 8] = *src;
            }
        }
    }
    __syncthreads();

    // ---- phase 2: offset conv via MFMA — ALL 4 waves: o-tile ot = wv&1, pixel-tile pt = wv>>1
    {
        int ot = wv & 1, pt = wv >> 1;
        int n = lane & 15, q = lane >> 4;
        const short8* Bw = (const short8*)OWb + (ot * 18) * 64 + lane;
        f32x4 acc = {0.f, 0.f, 0.f, 0.f};
#pragma unroll
        for (int s = 0; s < 18; ++s) {
            int k = s >> 1;
            int ky = k / 3, kx = k - ky * 3;
            int pix = ky * 34 + pt * 16 + n + kx;
            const short8 a = *(const short8*)&patch[pix * PROW + (s & 1) * 32 + q * 8];
            acc = __builtin_amdgcn_mfma_f32_16x16x32_bf16(a, Bw[s * 64], acc, 0, 0, 0);
        }
        int o = ot * 16 + n;
        if (o < 18) {
            float bo = offset_b[o];
#pragma unroll
            for (int r = 0; r < 4; ++r)
                offL[o * 32 + pt * 16 + q * 4 + r] = acc[r] + bo;
        }
    }
    __syncthreads();

    // ---- phase 4: sampling; 8 lanes/pixel; wave wv owns pixels wv*8+g8, ALL 9 taps
    // (two reg-batched chunks: taps 0..3 then 4..8 — perfectly wave-balanced)
    {
        int g8 = lane >> 3, c8 = lane & 7;
        int p = wv * 8 + g8;
        const __hip_bfloat16* xb8 = xBp + (size_t)b * (130 * 130 * 64) + c8 * 8 + 131 * 64;
        sample_taps<0, 4>(xb8, offL, sampB, h, w0, p, c8);
        sample_taps<4, 9>(xb8, offL, sampB, h, w0, p, c8);
    }
    __syncthreads();

    // ---- phase 5: einsum via MFMA; wave wv = o-tile; 2 pixel-tiles (shared B-frag)
    {
        int n = lane & 15, q = lane >> 4;
        const short8* BwW = (const short8*)Wb + (wv * 18) * 64 + lane;
        f32x4 acc0 = {0.f, 0.f, 0.f, 0.f};
        f32x4 acc1 = {0.f, 0.f, 0.f, 0.f};
#pragma unroll
        for (int s = 0; s < 18; ++s) {
            const short8 bw = BwW[s * 64];
            const short8 a0 = *(const short8*)&sampB[(s * 32 + n) * SROW + q * 8];
            const short8 a1 = *(const short8*)&sampB[(s * 32 + 16 + n) * SROW + q * 8];
            acc0 = __builtin_amdgcn_mfma_f32_16x16x32_bf16(a0, bw, acc0, 0, 0, 0);
            acc1 = __builtin_amdgcn_mfma_f32_16x16x32_bf16(a1, bw, acc1, 0, 0, 0);
        }
        int o = wv * 16 + n;
        float bo = bias[o];
        float* ob = &out[(((size_t)b * 64 + o) * 128 + h) * 128 + w0 + q * 4];
        float4 st0 = {acc0[0] + bo, acc0[1] + bo, acc0[2] + bo, acc0[3] + bo};
        float4 st1 = {acc1[0] + bo, acc1[1] + bo, acc1[2] + bo, acc1[3] + bo};
        *(float4*)ob = st0;
        *(float4*)(ob + 16) = st1;
    }
}

// ---------------------------------------------------------------- launch
extern "C" void kernel_launch(void* const* d_in, const int* in_sizes, int n_in,
                              void* d_out, int out_size, void* d_ws, size_t ws_size,
                              hipStream_t stream) {
    const float* x        = (const float*)d_in[0];
    const float* offset_w = (const float*)d_in[1];
    const float* offset_b = (const float*)d_in[2];
    const float* weight   = (const float*)d_in[3];
    const float* bias     = (const float*)d_in[4];
    char* ws = (char*)d_ws;
    __hip_bfloat16* xBp = (__hip_bfloat16*)ws;                          // 8,652,800 B
    __hip_bfloat16* Wb  = (__hip_bfloat16*)(ws + 8652800);              // 73,728 B
    __hip_bfloat16* OWb = (__hip_bfloat16*)(ws + 8652800 + 73728);      // 36,864 B
    float* outp = (float*)d_out;

    hipLaunchKernelGGL(prep_transpose_kernel, dim3(736),  dim3(256), 0, stream,
                       x, xBp, offset_w, weight, Wb, OWb);
    hipLaunchKernelGGL(deform_kernel,         dim3(2048), dim3(256), 0, stream,
                       xBp, Wb, OWb, offset_b, bias, outp);
}